// Round 7
// baseline (645.486 us; speedup 1.0000x reference)
//
#include <hip/hip_runtime.h>
#include <hip/hip_bf16.h>

// MHA forward via split-bf16 (hi+lo) MFMA. Round 7.
// B=4, S=2048, D_MODEL=1024, H=16, D_K=64.
// a*b ~= ah*bh + ah*bl + al*bh  (3x mfma_f32_16x16x32_bf16, fp32 accumulate)
//
// Round-7 changes:
//  - flash: QBLK 64->128, 8 waves/block (512 thr). Per-wave math identical to
//    the verified flash_mfma2; staging split across 8 waves. LDS still 32.25KB
//    -> 4 blocks/CU * 8 waves = 32 waves/CU target occupancy (was ~12.7).
//  - QKV projection GEMMs merged into ONE launch (grid 24x64, pointer select
//    per block) to remove launch gaps / tail under-fill.
//
// Workspace requirement: 144 MB.

#define SEQ   2048
#define DM    1024
#define NH    16
#define DK    64
#define MTOT  8192           // B*S

typedef unsigned short u16;
typedef __attribute__((ext_vector_type(8))) short bf16x8;
typedef __attribute__((ext_vector_type(4))) float f32x4;

typedef union { unsigned u[4]; bf16x8 v; } FragU;

#define MFMA(a, b, c) __builtin_amdgcn_mfma_f32_16x16x32_bf16((a), (b), (c), 0, 0, 0)

#if __has_builtin(__builtin_amdgcn_exp2f)
#define EXP2(x) __builtin_amdgcn_exp2f(x)
#else
#define EXP2(x) __expf((x) * 0.69314718056f)
#endif

__device__ __forceinline__ u16 f2bf(float v) {
    unsigned int x = __float_as_uint(v);
    x += 0x7fffu + ((x >> 16) & 1u);     // RNE
    return (u16)(x >> 16);
}
__device__ __forceinline__ float bf2f(u16 u) {
    return __uint_as_float(((unsigned int)u) << 16);
}
__device__ __forceinline__ unsigned pk2bf(float a, float b) {
    __hip_bfloat162 t = __float22bfloat162_rn(make_float2(a, b));
    unsigned r;
    __builtin_memcpy(&r, &t, 4);
    return r;
}

// async global->LDS, 16B per lane. LDS dest is wave-uniform base + lane*16.
__device__ __forceinline__ void gl_lds16(const void* g, void* l) {
    __builtin_amdgcn_global_load_lds((__attribute__((address_space(1))) void*)g,
                                     (__attribute__((address_space(3))) void*)l,
                                     16, 0, 0);
}

// ---------------------------------------------------------------------------
// split fp32 -> bf16 hi + bf16 lo (elementwise, float4/ushort4 vectorized)
// ---------------------------------------------------------------------------
__global__ __launch_bounds__(256) void split_f32(const float* __restrict__ src,
                                                 u16* __restrict__ dh,
                                                 u16* __restrict__ dl, int n4) {
    int i = blockIdx.x * 256 + threadIdx.x;
    if (i >= n4) return;
    float4 v = ((const float4*)src)[i];
    const float* f = (const float*)&v;
    ushort4 hh, ll;
    u16* hp = (u16*)&hh;
    u16* lp = (u16*)&ll;
#pragma unroll
    for (int j = 0; j < 4; ++j) {
        u16 h = f2bf(f[j]);
        hp[j] = h;
        lp[j] = f2bf(f[j] - bf2f(h));
    }
    ((ushort4*)dh)[i] = hh;
    ((ushort4*)dl)[i] = ll;
}

// ---------------------------------------------------------------------------
// Merged QKV GEMM: one launch, blockIdx.x 0..23 -> {W,bias,out} select.
// sel 0: Q -> [b,h,s,dk]; sel 1: K -> [b,h,s,dk]; sel 2: V -> [b,h,dk,s].
// Tile 128x128, BK=64, 256 threads (4 waves, 2x2), 4x4 frags of 16x16x32.
// ---------------------------------------------------------------------------
__global__ __launch_bounds__(256, 2) void gemm_qkv(
    const u16* __restrict__ Ah, const u16* __restrict__ Al,
    const u16* __restrict__ Wqh, const u16* __restrict__ Wql,
    const u16* __restrict__ Wkh, const u16* __restrict__ Wkl,
    const u16* __restrict__ Wvh, const u16* __restrict__ Wvl,
    const float* __restrict__ bq, const float* __restrict__ bk,
    const float* __restrict__ bv,
    u16* __restrict__ qh, u16* __restrict__ ql,
    u16* __restrict__ kh, u16* __restrict__ kl,
    u16* __restrict__ vh, u16* __restrict__ vl) {
    __shared__ u16 sm[4][128 * 64];   // Ahi, Alo, Bhi, Blo : 64 KB

    const int tid = threadIdx.x;
    const int w = tid >> 6, lane = tid & 63;
    const int bx = blockIdx.x;
    const int sel = bx >> 3;
    const int n0 = (bx & 7) * 128, m0 = blockIdx.y * 128;
    const int wr = w >> 1, wc = w & 1;
    const int rowoff = lane >> 3;
    const int cswz = ((lane & 7) ^ rowoff) << 3;

    const u16* Bh;
    const u16* Bl;
    const float* bias;
    u16* oH;
    u16* oL;
    if (sel == 0)      { Bh = Wqh; Bl = Wql; bias = bq; oH = qh; oL = ql; }
    else if (sel == 1) { Bh = Wkh; Bl = Wkl; bias = bk; oH = kh; oL = kl; }
    else               { Bh = Wvh; Bl = Wvl; bias = bv; oH = vh; oL = vl; }

    const u16* src = (w == 0) ? Ah : (w == 1) ? Al : (w == 2) ? Bh : Bl;
    const int row0 = (w < 2) ? m0 : n0;
    const u16* sbase = src + (size_t)(row0 + rowoff) * 1024 + cswz;

    f32x4 acc[4][4];
#pragma unroll
    for (int a = 0; a < 4; ++a)
#pragma unroll
        for (int b = 0; b < 4; ++b) acc[a][b] = (f32x4)0.f;

    for (int k0 = 0; k0 < 1024; k0 += 64) {
#pragma unroll
        for (int i = 0; i < 16; ++i)
            gl_lds16(sbase + (size_t)(8 * i) * 1024 + k0, &sm[w][i * 512]);
        __syncthreads();
#pragma unroll
        for (int kk = 0; kk < 2; ++kk) {
            bf16x8 ah[4], al[4], bh[4], bl[4];
#pragma unroll
            for (int t = 0; t < 4; ++t) {
                const int Ra = wr * 64 + t * 16 + (lane & 15);
                const int oa = Ra * 128 + ((((kk << 2) + (lane >> 4)) ^ (Ra & 7)) << 4);
                ah[t] = *(const bf16x8*)((const char*)&sm[0][0] + oa);
                al[t] = *(const bf16x8*)((const char*)&sm[1][0] + oa);
                const int Rb = wc * 64 + t * 16 + (lane & 15);
                const int ob = Rb * 128 + ((((kk << 2) + (lane >> 4)) ^ (Rb & 7)) << 4);
                bh[t] = *(const bf16x8*)((const char*)&sm[2][0] + ob);
                bl[t] = *(const bf16x8*)((const char*)&sm[3][0] + ob);
            }
#pragma unroll
            for (int mt = 0; mt < 4; ++mt)
#pragma unroll
                for (int nt = 0; nt < 4; ++nt) {
                    acc[mt][nt] = MFMA(ah[mt], bh[nt], acc[mt][nt]);
                    acc[mt][nt] = MFMA(ah[mt], bl[nt], acc[mt][nt]);
                    acc[mt][nt] = MFMA(al[mt], bh[nt], acc[mt][nt]);
                }
        }
        __syncthreads();
    }

    // epilogue. C layout: col = lane&15, row = (lane>>4)*4 + j
#pragma unroll
    for (int mt = 0; mt < 4; ++mt) {
#pragma unroll
        for (int nt = 0; nt < 4; ++nt) {
            const int n = n0 + wc * 64 + nt * 16 + (lane & 15);
            const float bvv = bias[n];
#pragma unroll
            for (int j = 0; j < 4; ++j) {
                const int m = m0 + wr * 64 + mt * 16 + (lane >> 4) * 4 + j;
                const float v = acc[mt][nt][j] + bvv;
                const u16 h16 = f2bf(v);
                const u16 l16 = f2bf(v - bf2f(h16));
                const int b = m >> 11, s = m & 2047, hh = n >> 6, dk = n & 63;
                size_t idx;
                if (sel != 2) idx = (((size_t)(b * 16 + hh)) * 2048 + s) * 64 + dk;
                else          idx = (((size_t)(b * 16 + hh)) * 64 + dk) * 2048 + s;
                oH[idx] = h16;
                oL[idx] = l16;
            }
        }
    }
}

// ---------------------------------------------------------------------------
// Output-projection GEMM (proven): fp32 out row-major.
// ---------------------------------------------------------------------------
__global__ __launch_bounds__(256, 2) void gemm_out(
    const u16* __restrict__ Ah, const u16* __restrict__ Al,
    const u16* __restrict__ Bh, const u16* __restrict__ Bl,
    const float* __restrict__ bias, float* __restrict__ outF) {
    __shared__ u16 sm[4][128 * 64];

    const int tid = threadIdx.x;
    const int w = tid >> 6, lane = tid & 63;
    const int n0 = blockIdx.x * 128, m0 = blockIdx.y * 128;
    const int wr = w >> 1, wc = w & 1;
    const int rowoff = lane >> 3;
    const int cswz = ((lane & 7) ^ rowoff) << 3;

    const u16* src = (w == 0) ? Ah : (w == 1) ? Al : (w == 2) ? Bh : Bl;
    const int row0 = (w < 2) ? m0 : n0;
    const u16* sbase = src + (size_t)(row0 + rowoff) * 1024 + cswz;

    f32x4 acc[4][4];
#pragma unroll
    for (int a = 0; a < 4; ++a)
#pragma unroll
        for (int b = 0; b < 4; ++b) acc[a][b] = (f32x4)0.f;

    for (int k0 = 0; k0 < 1024; k0 += 64) {
#pragma unroll
        for (int i = 0; i < 16; ++i)
            gl_lds16(sbase + (size_t)(8 * i) * 1024 + k0, &sm[w][i * 512]);
        __syncthreads();
#pragma unroll
        for (int kk = 0; kk < 2; ++kk) {
            bf16x8 ah[4], al[4], bh[4], bl[4];
#pragma unroll
            for (int t = 0; t < 4; ++t) {
                const int Ra = wr * 64 + t * 16 + (lane & 15);
                const int oa = Ra * 128 + ((((kk << 2) + (lane >> 4)) ^ (Ra & 7)) << 4);
                ah[t] = *(const bf16x8*)((const char*)&sm[0][0] + oa);
                al[t] = *(const bf16x8*)((const char*)&sm[1][0] + oa);
                const int Rb = wc * 64 + t * 16 + (lane & 15);
                const int ob = Rb * 128 + ((((kk << 2) + (lane >> 4)) ^ (Rb & 7)) << 4);
                bh[t] = *(const bf16x8*)((const char*)&sm[2][0] + ob);
                bl[t] = *(const bf16x8*)((const char*)&sm[3][0] + ob);
            }
#pragma unroll
            for (int mt = 0; mt < 4; ++mt)
#pragma unroll
                for (int nt = 0; nt < 4; ++nt) {
                    acc[mt][nt] = MFMA(ah[mt], bh[nt], acc[mt][nt]);
                    acc[mt][nt] = MFMA(ah[mt], bl[nt], acc[mt][nt]);
                    acc[mt][nt] = MFMA(al[mt], bh[nt], acc[mt][nt]);
                }
        }
        __syncthreads();
    }

#pragma unroll
    for (int mt = 0; mt < 4; ++mt) {
#pragma unroll
        for (int nt = 0; nt < 4; ++nt) {
            const int n = n0 + wc * 64 + nt * 16 + (lane & 15);
            const float bv = bias[n];
#pragma unroll
            for (int j = 0; j < 4; ++j) {
                const int m = m0 + wr * 64 + mt * 16 + (lane >> 4) * 4 + j;
                outF[(size_t)m * 1024 + n] = acc[mt][nt][j] + bv;
            }
        }
    }
}

// ---------------------------------------------------------------------------
// Flash attention v3: QBLK=128, 8 waves (512 threads), per-wave math identical
// to verified flash_mfma2. Wave w owns q-rows q0+w*16..+15, qrow_local=lane&15.
// KVBLK=64. Staging split: wave w stages chunks (w&1)*4..+3 of array (w>>1)
// (0=Kh 1=Kl 2=Vh 3=Vl). LDS: sK 16KB + sV 16KB + 256B mask = 32.25KB
// -> 4 blocks/CU * 8 waves = 32 waves/CU.
// ---------------------------------------------------------------------------
__global__ __launch_bounds__(512, 8) void flash_mfma3(
    const u16* __restrict__ Qh, const u16* __restrict__ Ql,
    const u16* __restrict__ Kh, const u16* __restrict__ Kl,
    const u16* __restrict__ Vh, const u16* __restrict__ Vl,
    const int* __restrict__ amask,
    u16* __restrict__ Ch, u16* __restrict__ Cl) {
    __shared__ u16 sK[2][64 * 64];       // 16 KB (rows = kcol, cols = dk)
    __shared__ u16 sV[2][64 * 64];       // 16 KB (rows = dk, cols = kcol)
    __shared__ unsigned sMask[64];       // 2048 mask bits

    const int tid = threadIdx.x, w = tid >> 6, lane = tid & 63;
    const int qt = blockIdx.x, bh = blockIdx.y;
    const int b = bh >> 4, h = bh & 15;
    const int q0 = qt * 128;
    const int hi = lane >> 4, l15 = lane & 15;
    const int rowoff = lane >> 3;
    const int cswz = ((lane & 7) ^ rowoff) << 3;
    const size_t kvbase = (size_t)bh * 2048;
    const float CE = 0.125f * 1.44269504089f;   // scale * log2(e)

    // build mask bitmask: thread t (<256) -> byte t (kcols 8t..8t+7)
    if (tid < 256) {
        const int* ap = amask + b * 2048 + tid * 8;
        int4 a0 = *(const int4*)ap;
        int4 a1 = *(const int4*)(ap + 4);
        unsigned byte = (unsigned)(a0.x != 0) | ((unsigned)(a0.y != 0) << 1) |
                        ((unsigned)(a0.z != 0) << 2) | ((unsigned)(a0.w != 0) << 3) |
                        ((unsigned)(a1.x != 0) << 4) | ((unsigned)(a1.y != 0) << 5) |
                        ((unsigned)(a1.z != 0) << 6) | ((unsigned)(a1.w != 0) << 7);
        ((unsigned char*)sMask)[tid] = (unsigned char)byte;
    }

    // hoist Q fragments (B-frag: col=l15 -> qrow, k = 32*kk + 8*hi + e)
    bf16x8 qfh[2], qfl[2];
    {
        const size_t qrow = kvbase + q0 + w * 16 + l15;
        const int koff = hi * 8;
#pragma unroll
        for (int kk = 0; kk < 2; ++kk) {
            qfh[kk] = *(const bf16x8*)(Qh + qrow * 64 + kk * 32 + koff);
            qfl[kk] = *(const bf16x8*)(Ql + qrow * 64 + kk * 32 + koff);
        }
    }

    // staging assignment: array arr = w>>1 (0=Kh 1=Kl 2=Vh 3=Vl), chunks c0..c0+3
    const int arr = w >> 1;
    const int c0 = (w & 1) * 4;
    const u16* ssrc = (arr == 0) ? Kh : (arr == 1) ? Kl : (arr == 2) ? Vh : Vl;
    u16* sdst = (arr == 0) ? &sK[0][0] : (arr == 1) ? &sK[1][0]
              : (arr == 2) ? &sV[0][0] : &sV[1][0];

    f32x4 o[4];
#pragma unroll
    for (int d = 0; d < 4; ++d) o[d] = (f32x4)0.f;
    float mi = -1e30f, li = 0.f;

    for (int kt = 0; kt < SEQ / 64; ++kt) {
        const int k0 = kt * 64;
        __syncthreads();   // prev iteration's LDS reads done (and mask, 1st iter)
        if (arr < 2) {
            const u16* sb = ssrc + (kvbase + k0 + 8 * c0 + rowoff) * 64 + cswz;
#pragma unroll
            for (int i = 0; i < 4; ++i)
                gl_lds16(sb + (size_t)(8 * i) * 64, sdst + (c0 + i) * 512);
        } else {
            const u16* sb = ssrc + ((size_t)bh * 64 + 8 * c0 + rowoff) * 2048 + k0 + cswz;
#pragma unroll
            for (int i = 0; i < 4; ++i)
                gl_lds16(sb + (size_t)(8 * i) * 2048, sdst + (c0 + i) * 512);
        }
        __syncthreads();

        // ---- S^T = K Q^T : s[nt][j] = S[kcol=16nt+4hi+j][qrow=l15] (raw) ----
        f32x4 s[4];
#pragma unroll
        for (int nt = 0; nt < 4; ++nt) s[nt] = (f32x4)0.f;
#pragma unroll
        for (int kk = 0; kk < 2; ++kk)
#pragma unroll
            for (int nt = 0; nt < 4; ++nt) {
                const int Rb = nt * 16 + l15;
                const int ob = Rb * 128 + ((((kk << 2) + hi) ^ (Rb & 7)) << 4);
                bf16x8 kbh = *(const bf16x8*)((const char*)&sK[0][0] + ob);
                bf16x8 kbl = *(const bf16x8*)((const char*)&sK[1][0] + ob);
                s[nt] = MFMA(kbh, qfh[kk], s[nt]);
                s[nt] = MFMA(kbh, qfl[kk], s[nt]);
                s[nt] = MFMA(kbl, qfh[kk], s[nt]);
            }

        // ---- mask (uniform all-ones fast path) ----
        const unsigned mlo = sMask[2 * kt], mhw = sMask[2 * kt + 1];
        if ((mlo & mhw) != 0xFFFFFFFFu) {
#pragma unroll
            for (int nt = 0; nt < 4; ++nt) {
                const unsigned mw = (nt & 2) ? mhw : mlo;
                const unsigned bits = mw >> (((nt & 1) << 4) + (hi << 2));
#pragma unroll
                for (int j = 0; j < 4; ++j)
                    if (!((bits >> j) & 1u)) s[nt][j] = -2e30f;
            }
        }

        // ---- online softmax, defer-max (THR = 64 raw = 8 scaled) ----
        float pm = s[0][0];
#pragma unroll
        for (int nt = 0; nt < 4; ++nt)
#pragma unroll
            for (int j = 0; j < 4; ++j) pm = fmaxf(pm, s[nt][j]);
        pm = fmaxf(pm, __shfl_xor(pm, 16));
        pm = fmaxf(pm, __shfl_xor(pm, 32));
        if (__any(pm > mi + 64.f)) {
            const float mnew = fmaxf(mi, pm);
            const float sc = EXP2((mi - mnew) * CE);
            li *= sc;
#pragma unroll
            for (int d = 0; d < 4; ++d) o[d] *= sc;
            mi = mnew;
        }
        const float nm = -mi * CE;
        float p[4][4];
        float rs = 0.f;
#pragma unroll
        for (int nt = 0; nt < 4; ++nt)
#pragma unroll
            for (int j = 0; j < 4; ++j) {
                const float e = EXP2(fmaf(s[nt][j], CE, nm));
                p[nt][j] = e;
                rs += e;
            }
        rs += __shfl_xor(rs, 16);
        rs += __shfl_xor(rs, 32);
        li += rs;

        // ---- pack P to bf16 hi/lo pairs: qph/qpl[nt][c] = kcols 16nt+4hi+2c,+1 ----
        unsigned qph[4][2], qpl[4][2];
#pragma unroll
        for (int nt = 0; nt < 4; ++nt)
#pragma unroll
            for (int c = 0; c < 2; ++c) {
                const float v0 = p[nt][2 * c], v1 = p[nt][2 * c + 1];
                const unsigned wh = pk2bf(v0, v1);
                qph[nt][c] = wh;
                const float r0 = v0 - __uint_as_float(wh << 16);
                const float r1 = v1 - __uint_as_float(wh & 0xffff0000u);
                qpl[nt][c] = pk2bf(r0, r1);
            }

        // ---- redistribute to PV B-frags and accumulate O^T ----
        const int src01 = l15 | ((lane & 16) << 1);   // l15 + 32*(hi&1)
        const int src23 = src01 + 16;
#pragma unroll
        for (int kkv = 0; kkv < 2; ++kkv) {
            const unsigned ah0 = __shfl(qph[2 * kkv][0], src01);
            const unsigned ah1 = __shfl(qph[2 * kkv][1], src01);
            const unsigned ah2 = __shfl(qph[2 * kkv][0], src23);
            const unsigned ah3 = __shfl(qph[2 * kkv][1], src23);
            const unsigned bh0 = __shfl(qph[2 * kkv + 1][0], src01);
            const unsigned bh1 = __shfl(qph[2 * kkv + 1][1], src01);
            const unsigned bh2 = __shfl(qph[2 * kkv + 1][0], src23);
            const unsigned bh3 = __shfl(qph[2 * kkv + 1][1], src23);
            const unsigned al0 = __shfl(qpl[2 * kkv][0], src01);
            const unsigned al1 = __shfl(qpl[2 * kkv][1], src01);
            const unsigned al2 = __shfl(qpl[2 * kkv][0], src23);
            const unsigned al3 = __shfl(qpl[2 * kkv][1], src23);
            const unsigned bl0 = __shfl(qpl[2 * kkv + 1][0], src01);
            const unsigned bl1 = __shfl(qpl[2 * kkv + 1][1], src01);
            const unsigned bl2 = __shfl(qpl[2 * kkv + 1][0], src23);
            const unsigned bl3 = __shfl(qpl[2 * kkv + 1][1], src23);
            const bool up = (hi >= 2);
            FragU uh, ul;
            uh.u[0] = up ? bh0 : ah0;
            uh.u[1] = up ? bh1 : ah1;
            uh.u[2] = up ? bh2 : ah2;
            uh.u[3] = up ? bh3 : ah3;
            ul.u[0] = up ? bl0 : al0;
            ul.u[1] = up ? bl1 : al1;
            ul.u[2] = up ? bl2 : al2;
            ul.u[3] = up ? bl3 : al3;
            const bf16x8 pbh = uh.v, pbl = ul.v;
#pragma unroll
            for (int ntd = 0; ntd < 4; ++ntd) {
                const int Rv = ntd * 16 + l15;
                const int ov = Rv * 128 + ((((kkv << 2) + hi) ^ (Rv & 7)) << 4);
                bf16x8 vbh = *(const bf16x8*)((const char*)&sV[0][0] + ov);
                bf16x8 vbl = *(const bf16x8*)((const char*)&sV[1][0] + ov);
                o[ntd] = MFMA(vbh, pbh, o[ntd]);
                o[ntd] = MFMA(vbh, pbl, o[ntd]);
                o[ntd] = MFMA(vbl, pbh, o[ntd]);
            }
        }
    }

    // ---- epilogue: normalize, packed hi/lo writes (8 B each) ----
    const float inv = 1.f / li;
    const int srow = q0 + w * 16 + l15;
    const size_t obase = ((size_t)b * 2048 + srow) * 1024 + h * 64;
#pragma unroll
    for (int ntd = 0; ntd < 4; ++ntd) {
        const float v0 = o[ntd][0] * inv, v1 = o[ntd][1] * inv;
        const float v2 = o[ntd][2] * inv, v3 = o[ntd][3] * inv;
        const unsigned wh0 = pk2bf(v0, v1), wh1 = pk2bf(v2, v3);
        const float r0 = v0 - __uint_as_float(wh0 << 16);
        const float r1 = v1 - __uint_as_float(wh0 & 0xffff0000u);
        const float r2 = v2 - __uint_as_float(wh1 << 16);
        const float r3 = v3 - __uint_as_float(wh1 & 0xffff0000u);
        const unsigned wl0 = pk2bf(r0, r1), wl1 = pk2bf(r2, r3);
        const size_t idx = obase + ntd * 16 + hi * 4;
        uint2 sh, sl;
        sh.x = wh0; sh.y = wh1;
        sl.x = wl0; sl.y = wl1;
        *(uint2*)&Ch[idx] = sh;
        *(uint2*)&Cl[idx] = sl;
    }
}

// ---------------------------------------------------------------------------
extern "C" void kernel_launch(void* const* d_in, const int* in_sizes, int n_in,
                              void* d_out, int out_size, void* d_ws, size_t ws_size,
                              hipStream_t stream) {
    const float* x  = (const float*)d_in[0];
    const int* am   = (const int*)d_in[1];
    const float* Wq = (const float*)d_in[2];
    const float* bq = (const float*)d_in[3];
    const float* Wk = (const float*)d_in[4];
    const float* bk = (const float*)d_in[5];
    const float* Wv = (const float*)d_in[6];
    const float* bv = (const float*)d_in[7];
    const float* Wo = (const float*)d_in[8];
    const float* bo = (const float*)d_in[9];
    float* out = (float*)d_out;

    const size_t MB = 1u << 20;
    char* ws = (char*)d_ws;
    u16* Xh  = (u16*)(ws + 0 * MB);      // 16 MB   (reused as ctx hi)
    u16* Xl  = (u16*)(ws + 16 * MB);     // 16 MB   (reused as ctx lo)
    u16* qh  = (u16*)(ws + 32 * MB);
    u16* ql  = (u16*)(ws + 48 * MB);
    u16* kh  = (u16*)(ws + 64 * MB);
    u16* kl  = (u16*)(ws + 80 * MB);
    u16* vh  = (u16*)(ws + 96 * MB);     // transposed [b,h,dk,s]
    u16* vl  = (u16*)(ws + 112 * MB);
    u16* Wqh = (u16*)(ws + 128 * MB);
    u16* Wql = (u16*)(ws + 130 * MB);
    u16* Wkh = (u16*)(ws + 132 * MB);
    u16* Wkl = (u16*)(ws + 134 * MB);
    u16* Wvh = (u16*)(ws + 136 * MB);
    u16* Wvl = (u16*)(ws + 138 * MB);
    u16* Woh = (u16*)(ws + 140 * MB);
    u16* Wol = (u16*)(ws + 142 * MB);    // total 144 MB

    // split inputs to bf16 hi/lo
    split_f32<<<(MTOT * DM / 4 + 255) / 256, 256, 0, stream>>>(x, Xh, Xl, MTOT * DM / 4);
    split_f32<<<(DM * DM / 4 + 255) / 256, 256, 0, stream>>>(Wq, Wqh, Wql, DM * DM / 4);
    split_f32<<<(DM * DM / 4 + 255) / 256, 256, 0, stream>>>(Wk, Wkh, Wkl, DM * DM / 4);
    split_f32<<<(DM * DM / 4 + 255) / 256, 256, 0, stream>>>(Wv, Wvh, Wvl, DM * DM / 4);
    split_f32<<<(DM * DM / 4 + 255) / 256, 256, 0, stream>>>(Wo, Woh, Wol, DM * DM / 4);

    // merged QKV projection (24 n-tiles: 8 Q, 8 K, 8 V)
    gemm_qkv<<<dim3(24, MTOT / 128), 256, 0, stream>>>(
        Xh, Xl, Wqh, Wql, Wkh, Wkl, Wvh, Wvl, bq, bk, bv,
        qh, ql, kh, kl, vh, vl);

    flash_mfma3<<<dim3(SEQ / 128, 4 * NH), 512, 0, stream>>>(qh, ql, kh, kl, vh, vl, am, Xh, Xl);

    gemm_out<<<dim3(DM / 128, MTOT / 128), 256, 0, stream>>>(Xh, Xl, Woh, Wol, bo, out);
}

// Round 8
// 549.274 us; speedup vs baseline: 1.1752x; 1.1752x over previous
//
#include <hip/hip_runtime.h>
#include <hip/hip_bf16.h>

// MHA forward via split-bf16 (hi+lo) MFMA. Round 8.
// B=4, S=2048, D_MODEL=1024, H=16, D_K=64.
// a*b ~= ah*bh + ah*bl + al*bh  (3x mfma_f32_16x16x32_bf16, fp32 accumulate)
//
// Round-8 changes (flash is LDS-pipe-bound: occupancy 39.7->74.6% gave 0 gain):
//  - flash_mfma4: 2 q-strips per wave (32 q-rows). Each K/V fragment load from
//    LDS feeds 6 MFMAs (2 strips x 3 split-terms) instead of 3 -> total LDS
//    ds_read_b128 volume HALVED. Per-lane math identical to verified v2 code.
//  - XCD-aware block remap in flash (same-bh blocks grouped on one XCD,
//    qt-major in time) to cut L2 thrash (FETCH_SIZE 611 MB regression).
//  - Reverted merged-QKV launch (+55 us regression in round 7): back to
//    3x gemm_split<1|2> + gemm_split<0> as in the 590-us round-6 pipeline.
//
// Workspace requirement: 144 MB.

#define SEQ   2048
#define DM    1024
#define NH    16
#define DK    64
#define MTOT  8192           // B*S

typedef unsigned short u16;
typedef __attribute__((ext_vector_type(8))) short bf16x8;
typedef __attribute__((ext_vector_type(4))) float f32x4;

typedef union { unsigned u[4]; bf16x8 v; } FragU;

#define MFMA(a, b, c) __builtin_amdgcn_mfma_f32_16x16x32_bf16((a), (b), (c), 0, 0, 0)

#if __has_builtin(__builtin_amdgcn_exp2f)
#define EXP2(x) __builtin_amdgcn_exp2f(x)
#else
#define EXP2(x) __expf((x) * 0.69314718056f)
#endif

__device__ __forceinline__ u16 f2bf(float v) {
    unsigned int x = __float_as_uint(v);
    x += 0x7fffu + ((x >> 16) & 1u);     // RNE
    return (u16)(x >> 16);
}
__device__ __forceinline__ float bf2f(u16 u) {
    return __uint_as_float(((unsigned int)u) << 16);
}
__device__ __forceinline__ unsigned pk2bf(float a, float b) {
    __hip_bfloat162 t = __float22bfloat162_rn(make_float2(a, b));
    unsigned r;
    __builtin_memcpy(&r, &t, 4);
    return r;
}

// async global->LDS, 16B per lane. LDS dest is wave-uniform base + lane*16.
__device__ __forceinline__ void gl_lds16(const void* g, void* l) {
    __builtin_amdgcn_global_load_lds((__attribute__((address_space(1))) void*)g,
                                     (__attribute__((address_space(3))) void*)l,
                                     16, 0, 0);
}

// ---------------------------------------------------------------------------
// split fp32 -> bf16 hi + bf16 lo (elementwise, float4/ushort4 vectorized)
// ---------------------------------------------------------------------------
__global__ __launch_bounds__(256) void split_f32(const float* __restrict__ src,
                                                 u16* __restrict__ dh,
                                                 u16* __restrict__ dl, int n4) {
    int i = blockIdx.x * 256 + threadIdx.x;
    if (i >= n4) return;
    float4 v = ((const float4*)src)[i];
    const float* f = (const float*)&v;
    ushort4 hh, ll;
    u16* hp = (u16*)&hh;
    u16* lp = (u16*)&ll;
#pragma unroll
    for (int j = 0; j < 4; ++j) {
        u16 h = f2bf(f[j]);
        hp[j] = h;
        lp[j] = f2bf(f[j] - bf2f(h));
    }
    ((ushort4*)dh)[i] = hh;
    ((ushort4*)dl)[i] = ll;
}

// ---------------------------------------------------------------------------
// GEMM (proven round 2/6): C[m,n] = sum_k A[m,k]*W[n,k] + bias[n].
// Tile 128x128, BK=64, 256 threads (4 waves, 2x2), 4x4 frags of 16x16x32.
// MODE 0: fp32 out row-major. MODE 1: bf16 hi/lo out [b,h,s,dk].
// MODE 2: bf16 hi/lo out [b,h,dk,s] (transposed, for V).
// ---------------------------------------------------------------------------
template <int MODE>
__global__ __launch_bounds__(256, 2) void gemm_split(
    const u16* __restrict__ Ah, const u16* __restrict__ Al,
    const u16* __restrict__ Bh, const u16* __restrict__ Bl,
    const float* __restrict__ bias,
    float* __restrict__ outF, u16* __restrict__ outH, u16* __restrict__ outL) {
    __shared__ u16 sm[4][128 * 64];   // Ahi, Alo, Bhi, Blo : 64 KB

    const int tid = threadIdx.x;
    const int w = tid >> 6, lane = tid & 63;
    const int n0 = blockIdx.x * 128, m0 = blockIdx.y * 128;
    const int wr = w >> 1, wc = w & 1;
    const int rowoff = lane >> 3;                       // 0..7
    const int cswz = ((lane & 7) ^ rowoff) << 3;        // element offset of 8-elem chunk

    const u16* src = (w == 0) ? Ah : (w == 1) ? Al : (w == 2) ? Bh : Bl;
    const int row0 = (w < 2) ? m0 : n0;
    const u16* sbase = src + (size_t)(row0 + rowoff) * 1024 + cswz;

    f32x4 acc[4][4];
#pragma unroll
    for (int a = 0; a < 4; ++a)
#pragma unroll
        for (int b = 0; b < 4; ++b) acc[a][b] = (f32x4)0.f;

    for (int k0 = 0; k0 < 1024; k0 += 64) {
#pragma unroll
        for (int i = 0; i < 16; ++i)
            gl_lds16(sbase + (size_t)(8 * i) * 1024 + k0, &sm[w][i * 512]);
        __syncthreads();   // drains vmcnt: staged tile visible
#pragma unroll
        for (int kk = 0; kk < 2; ++kk) {
            bf16x8 ah[4], al[4], bh[4], bl[4];
#pragma unroll
            for (int t = 0; t < 4; ++t) {
                const int Ra = wr * 64 + t * 16 + (lane & 15);
                const int oa = Ra * 128 + ((((kk << 2) + (lane >> 4)) ^ (Ra & 7)) << 4);
                ah[t] = *(const bf16x8*)((const char*)&sm[0][0] + oa);
                al[t] = *(const bf16x8*)((const char*)&sm[1][0] + oa);
                const int Rb = wc * 64 + t * 16 + (lane & 15);
                const int ob = Rb * 128 + ((((kk << 2) + (lane >> 4)) ^ (Rb & 7)) << 4);
                bh[t] = *(const bf16x8*)((const char*)&sm[2][0] + ob);
                bl[t] = *(const bf16x8*)((const char*)&sm[3][0] + ob);
            }
#pragma unroll
            for (int mt = 0; mt < 4; ++mt)
#pragma unroll
                for (int nt = 0; nt < 4; ++nt) {
                    acc[mt][nt] = MFMA(ah[mt], bh[nt], acc[mt][nt]);
                    acc[mt][nt] = MFMA(ah[mt], bl[nt], acc[mt][nt]);
                    acc[mt][nt] = MFMA(al[mt], bh[nt], acc[mt][nt]);
                }
        }
        __syncthreads();   // LDS reads done before next staging
    }

    // epilogue. C layout: col = lane&15, row = (lane>>4)*4 + j
#pragma unroll
    for (int mt = 0; mt < 4; ++mt) {
#pragma unroll
        for (int nt = 0; nt < 4; ++nt) {
            const int n = n0 + wc * 64 + nt * 16 + (lane & 15);
            const float bv = bias[n];
#pragma unroll
            for (int j = 0; j < 4; ++j) {
                const int m = m0 + wr * 64 + mt * 16 + (lane >> 4) * 4 + j;
                const float v = acc[mt][nt][j] + bv;
                if (MODE == 0) {
                    outF[(size_t)m * 1024 + n] = v;
                } else {
                    const u16 h16 = f2bf(v);
                    const u16 l16 = f2bf(v - bf2f(h16));
                    const int b = m >> 11, s = m & 2047, hh = n >> 6, dk = n & 63;
                    size_t idx;
                    if (MODE == 1) idx = (((size_t)(b * 16 + hh)) * 2048 + s) * 64 + dk;
                    else           idx = (((size_t)(b * 16 + hh)) * 64 + dk) * 2048 + s;
                    outH[idx] = h16;
                    outL[idx] = l16;
                }
            }
        }
    }
}

// ---------------------------------------------------------------------------
// Flash attention v4: 4 waves x 32 q-rows (TWO 16-row strips per wave).
// Each K/V LDS fragment load feeds 6 MFMAs (2 strips x 3 split terms) ->
// LDS read volume per q-row halved vs v2/v3 (the measured binder).
// Per-strip math is byte-identical to the verified flash_mfma2 lane code.
// Block = 256 thr; QBLK = 128 (4 waves x 32 rows); KVBLK = 64.
// XCD remap: flat id i -> xcd = i&7; same-bh blocks share an XCD, qt-major.
// LDS: sK 16KB + sV 16KB + 256B mask = 32.25 KB.
// ---------------------------------------------------------------------------
__global__ __launch_bounds__(256, 2) void flash_mfma4(
    const u16* __restrict__ Qh, const u16* __restrict__ Ql,
    const u16* __restrict__ Kh, const u16* __restrict__ Kl,
    const u16* __restrict__ Vh, const u16* __restrict__ Vl,
    const int* __restrict__ amask,
    u16* __restrict__ Ch, u16* __restrict__ Cl) {
    __shared__ u16 sK[2][64 * 64];       // 16 KB (rows = kcol, cols = dk)
    __shared__ u16 sV[2][64 * 64];       // 16 KB (rows = dk, cols = kcol)
    __shared__ unsigned sMask[64];       // 2048 mask bits

    const int tid = threadIdx.x, w = tid >> 6, lane = tid & 63;
    // XCD-aware remap of (qt, bh): i = x + 8*j; xcd x gets bh in [x*8, x*8+8),
    // 16 consecutive j = same bh (qt 0..15) -> per-XCD K/V working set ~1MB.
    const int i_flat = blockIdx.x + 16 * blockIdx.y;
    const int xcd = i_flat & 7, j_rem = i_flat >> 3;
    const int bh = xcd * 8 + (j_rem >> 4);
    const int qt = j_rem & 15;
    const int b = bh >> 4, h = bh & 15;
    const int q0 = qt * 128;
    const int hi = lane >> 4, l15 = lane & 15;
    const int rowoff = lane >> 3;
    const int cswz = ((lane & 7) ^ rowoff) << 3;
    const size_t kvbase = (size_t)bh * 2048;
    const float CE = 0.125f * 1.44269504089f;   // scale * log2(e)

    // build mask bitmask: thread t -> byte t (kcols 8t..8t+7)
    {
        const int* ap = amask + b * 2048 + tid * 8;
        int4 a0 = *(const int4*)ap;
        int4 a1 = *(const int4*)(ap + 4);
        unsigned byte = (unsigned)(a0.x != 0) | ((unsigned)(a0.y != 0) << 1) |
                        ((unsigned)(a0.z != 0) << 2) | ((unsigned)(a0.w != 0) << 3) |
                        ((unsigned)(a1.x != 0) << 4) | ((unsigned)(a1.y != 0) << 5) |
                        ((unsigned)(a1.z != 0) << 6) | ((unsigned)(a1.w != 0) << 7);
        ((unsigned char*)sMask)[tid] = (unsigned char)byte;
    }

    // hoist Q fragments, both strips (B-frag: col=l15 -> qrow, k=32*kk+8*hi+e)
    bf16x8 qfh[2][2], qfl[2][2];   // [strip][kk]
#pragma unroll
    for (int st = 0; st < 2; ++st) {
        const size_t qrow = kvbase + q0 + w * 32 + st * 16 + l15;
        const int koff = hi * 8;
#pragma unroll
        for (int kk = 0; kk < 2; ++kk) {
            qfh[st][kk] = *(const bf16x8*)(Qh + qrow * 64 + kk * 32 + koff);
            qfl[st][kk] = *(const bf16x8*)(Ql + qrow * 64 + kk * 32 + koff);
        }
    }

    f32x4 o[2][4];
    float mi[2], li[2];
#pragma unroll
    for (int st = 0; st < 2; ++st) {
        mi[st] = -1e30f;
        li[st] = 0.f;
#pragma unroll
        for (int d = 0; d < 4; ++d) o[st][d] = (f32x4)0.f;
    }

    for (int kt = 0; kt < SEQ / 64; ++kt) {
        const int k0 = kt * 64;
        __syncthreads();   // prev iteration's LDS reads done (and mask, 1st iter)
        {
            // wave w stages tile w: 0=Kh 1=Kl 2=Vh 3=Vl (8 chunks each)
            const u16* src = (w == 0) ? Kh : (w == 1) ? Kl : (w == 2) ? Vh : Vl;
            u16* dst = (w == 0) ? &sK[0][0] : (w == 1) ? &sK[1][0]
                     : (w == 2) ? &sV[0][0] : &sV[1][0];
            if (w < 2) {
                const u16* sb = src + (kvbase + k0 + rowoff) * 64 + cswz;
#pragma unroll
                for (int i = 0; i < 8; ++i)
                    gl_lds16(sb + (size_t)(8 * i) * 64, dst + i * 512);
            } else {
                const u16* sb = src + ((size_t)bh * 64 + rowoff) * 2048 + k0 + cswz;
#pragma unroll
                for (int i = 0; i < 8; ++i)
                    gl_lds16(sb + (size_t)(8 * i) * 2048, dst + i * 512);
            }
        }
        __syncthreads();

        // ---- S^T = K Q^T : s[st][nt][j] = S[kcol=16nt+4hi+j][qrow(st)=l15] ----
        f32x4 s[2][4];
#pragma unroll
        for (int st = 0; st < 2; ++st)
#pragma unroll
            for (int nt = 0; nt < 4; ++nt) s[st][nt] = (f32x4)0.f;
#pragma unroll
        for (int kk = 0; kk < 2; ++kk)
#pragma unroll
            for (int nt = 0; nt < 4; ++nt) {
                const int Rb = nt * 16 + l15;
                const int ob = Rb * 128 + ((((kk << 2) + hi) ^ (Rb & 7)) << 4);
                bf16x8 kbh = *(const bf16x8*)((const char*)&sK[0][0] + ob);
                bf16x8 kbl = *(const bf16x8*)((const char*)&sK[1][0] + ob);
                s[0][nt] = MFMA(kbh, qfh[0][kk], s[0][nt]);
                s[0][nt] = MFMA(kbh, qfl[0][kk], s[0][nt]);
                s[0][nt] = MFMA(kbl, qfh[0][kk], s[0][nt]);
                s[1][nt] = MFMA(kbh, qfh[1][kk], s[1][nt]);
                s[1][nt] = MFMA(kbh, qfl[1][kk], s[1][nt]);
                s[1][nt] = MFMA(kbl, qfh[1][kk], s[1][nt]);
            }

        // ---- mask (uniform all-ones fast path) ----
        const unsigned mlo = sMask[2 * kt], mhw = sMask[2 * kt + 1];
        if ((mlo & mhw) != 0xFFFFFFFFu) {
#pragma unroll
            for (int nt = 0; nt < 4; ++nt) {
                const unsigned mw = (nt & 2) ? mhw : mlo;
                const unsigned bits = mw >> (((nt & 1) << 4) + (hi << 2));
#pragma unroll
                for (int j = 0; j < 4; ++j)
                    if (!((bits >> j) & 1u)) {
                        s[0][nt][j] = -2e30f;
                        s[1][nt][j] = -2e30f;
                    }
            }
        }

        // ---- per-strip online softmax (defer-max THR=64 raw) + pack + PV-prep
        unsigned qph[2][4][2], qpl[2][4][2];
#pragma unroll
        for (int st = 0; st < 2; ++st) {
            float pm = s[st][0][0];
#pragma unroll
            for (int nt = 0; nt < 4; ++nt)
#pragma unroll
                for (int j = 0; j < 4; ++j) pm = fmaxf(pm, s[st][nt][j]);
            pm = fmaxf(pm, __shfl_xor(pm, 16));
            pm = fmaxf(pm, __shfl_xor(pm, 32));
            if (__any(pm > mi[st] + 64.f)) {
                const float mnew = fmaxf(mi[st], pm);
                const float sc = EXP2((mi[st] - mnew) * CE);
                li[st] *= sc;
#pragma unroll
                for (int d = 0; d < 4; ++d) o[st][d] *= sc;
                mi[st] = mnew;
            }
            const float nm = -mi[st] * CE;
            float p[4][4];
            float rs = 0.f;
#pragma unroll
            for (int nt = 0; nt < 4; ++nt)
#pragma unroll
                for (int j = 0; j < 4; ++j) {
                    const float e = EXP2(fmaf(s[st][nt][j], CE, nm));
                    p[nt][j] = e;
                    rs += e;
                }
            rs += __shfl_xor(rs, 16);
            rs += __shfl_xor(rs, 32);
            li[st] += rs;

            // pack P to bf16 hi/lo pairs: qp*[st][nt][c] = kcols 16nt+4hi+2c,+1
#pragma unroll
            for (int nt = 0; nt < 4; ++nt)
#pragma unroll
                for (int c = 0; c < 2; ++c) {
                    const float v0 = p[nt][2 * c], v1 = p[nt][2 * c + 1];
                    const unsigned wh = pk2bf(v0, v1);
                    qph[st][nt][c] = wh;
                    const float r0 = v0 - __uint_as_float(wh << 16);
                    const float r1 = v1 - __uint_as_float(wh & 0xffff0000u);
                    qpl[st][nt][c] = pk2bf(r0, r1);
                }
        }

        // ---- redistribute to PV B-frags; each V frag load feeds 6 MFMAs ----
        const int src01 = l15 | ((lane & 16) << 1);   // l15 + 32*(hi&1)
        const int src23 = src01 + 16;
#pragma unroll
        for (int kkv = 0; kkv < 2; ++kkv) {
            bf16x8 pbh[2], pbl[2];
#pragma unroll
            for (int st = 0; st < 2; ++st) {
                const unsigned ah0 = __shfl(qph[st][2 * kkv][0], src01);
                const unsigned ah1 = __shfl(qph[st][2 * kkv][1], src01);
                const unsigned ah2 = __shfl(qph[st][2 * kkv][0], src23);
                const unsigned ah3 = __shfl(qph[st][2 * kkv][1], src23);
                const unsigned bh0 = __shfl(qph[st][2 * kkv + 1][0], src01);
                const unsigned bh1 = __shfl(qph[st][2 * kkv + 1][1], src01);
                const unsigned bh2 = __shfl(qph[st][2 * kkv + 1][0], src23);
                const unsigned bh3 = __shfl(qph[st][2 * kkv + 1][1], src23);
                const unsigned al0 = __shfl(qpl[st][2 * kkv][0], src01);
                const unsigned al1 = __shfl(qpl[st][2 * kkv][1], src01);
                const unsigned al2 = __shfl(qpl[st][2 * kkv][0], src23);
                const unsigned al3 = __shfl(qpl[st][2 * kkv][1], src23);
                const unsigned bl0 = __shfl(qpl[st][2 * kkv + 1][0], src01);
                const unsigned bl1 = __shfl(qpl[st][2 * kkv + 1][1], src01);
                const unsigned bl2 = __shfl(qpl[st][2 * kkv + 1][0], src23);
                const unsigned bl3 = __shfl(qpl[st][2 * kkv + 1][1], src23);
                const bool up = (hi >= 2);
                FragU uh, ul;
                uh.u[0] = up ? bh0 : ah0;
                uh.u[1] = up ? bh1 : ah1;
                uh.u[2] = up ? bh2 : ah2;
                uh.u[3] = up ? bh3 : ah3;
                ul.u[0] = up ? bl0 : al0;
                ul.u[1] = up ? bl1 : al1;
                ul.u[2] = up ? bl2 : al2;
                ul.u[3] = up ? bl3 : al3;
                pbh[st] = uh.v;
                pbl[st] = ul.v;
            }
#pragma unroll
            for (int ntd = 0; ntd < 4; ++ntd) {
                const int Rv = ntd * 16 + l15;
                const int ov = Rv * 128 + ((((kkv << 2) + hi) ^ (Rv & 7)) << 4);
                bf16x8 vbh = *(const bf16x8*)((const char*)&sV[0][0] + ov);
                bf16x8 vbl = *(const bf16x8*)((const char*)&sV[1][0] + ov);
                o[0][ntd] = MFMA(vbh, pbh[0], o[0][ntd]);
                o[0][ntd] = MFMA(vbh, pbl[0], o[0][ntd]);
                o[0][ntd] = MFMA(vbl, pbh[0], o[0][ntd]);
                o[1][ntd] = MFMA(vbh, pbh[1], o[1][ntd]);
                o[1][ntd] = MFMA(vbh, pbl[1], o[1][ntd]);
                o[1][ntd] = MFMA(vbl, pbh[1], o[1][ntd]);
            }
        }
    }

    // ---- epilogue: normalize, packed hi/lo writes (8 B each), both strips ----
#pragma unroll
    for (int st = 0; st < 2; ++st) {
        const float inv = 1.f / li[st];
        const int srow = q0 + w * 32 + st * 16 + l15;
        const size_t obase = ((size_t)b * 2048 + srow) * 1024 + h * 64;
#pragma unroll
        for (int ntd = 0; ntd < 4; ++ntd) {
            const float v0 = o[st][ntd][0] * inv, v1 = o[st][ntd][1] * inv;
            const float v2 = o[st][ntd][2] * inv, v3 = o[st][ntd][3] * inv;
            const unsigned wh0 = pk2bf(v0, v1), wh1 = pk2bf(v2, v3);
            const float r0 = v0 - __uint_as_float(wh0 << 16);
            const float r1 = v1 - __uint_as_float(wh0 & 0xffff0000u);
            const float r2 = v2 - __uint_as_float(wh1 << 16);
            const float r3 = v3 - __uint_as_float(wh1 & 0xffff0000u);
            const unsigned wl0 = pk2bf(r0, r1), wl1 = pk2bf(r2, r3);
            const size_t idx = obase + ntd * 16 + hi * 4;
            uint2 sh, sl;
            sh.x = wh0; sh.y = wh1;
            sl.x = wl0; sl.y = wl1;
            *(uint2*)&Ch[idx] = sh;
            *(uint2*)&Cl[idx] = sl;
        }
    }
}

// ---------------------------------------------------------------------------
extern "C" void kernel_launch(void* const* d_in, const int* in_sizes, int n_in,
                              void* d_out, int out_size, void* d_ws, size_t ws_size,
                              hipStream_t stream) {
    const float* x  = (const float*)d_in[0];
    const int* am   = (const int*)d_in[1];
    const float* Wq = (const float*)d_in[2];
    const float* bq = (const float*)d_in[3];
    const float* Wk = (const float*)d_in[4];
    const float* bk = (const float*)d_in[5];
    const float* Wv = (const float*)d_in[6];
    const float* bv = (const float*)d_in[7];
    const float* Wo = (const float*)d_in[8];
    const float* bo = (const float*)d_in[9];
    float* out = (float*)d_out;

    const size_t MB = 1u << 20;
    char* ws = (char*)d_ws;
    u16* Xh  = (u16*)(ws + 0 * MB);      // 16 MB   (reused as ctx hi)
    u16* Xl  = (u16*)(ws + 16 * MB);     // 16 MB   (reused as ctx lo)
    u16* qh  = (u16*)(ws + 32 * MB);
    u16* ql  = (u16*)(ws + 48 * MB);
    u16* kh  = (u16*)(ws + 64 * MB);
    u16* kl  = (u16*)(ws + 80 * MB);
    u16* vh  = (u16*)(ws + 96 * MB);     // transposed [b,h,dk,s]
    u16* vl  = (u16*)(ws + 112 * MB);
    u16* Wqh = (u16*)(ws + 128 * MB);
    u16* Wql = (u16*)(ws + 130 * MB);
    u16* Wkh = (u16*)(ws + 132 * MB);
    u16* Wkl = (u16*)(ws + 134 * MB);
    u16* Wvh = (u16*)(ws + 136 * MB);
    u16* Wvl = (u16*)(ws + 138 * MB);
    u16* Woh = (u16*)(ws + 140 * MB);
    u16* Wol = (u16*)(ws + 142 * MB);    // total 144 MB

    // split inputs to bf16 hi/lo
    split_f32<<<(MTOT * DM / 4 + 255) / 256, 256, 0, stream>>>(x, Xh, Xl, MTOT * DM / 4);
    split_f32<<<(DM * DM / 4 + 255) / 256, 256, 0, stream>>>(Wq, Wqh, Wql, DM * DM / 4);
    split_f32<<<(DM * DM / 4 + 255) / 256, 256, 0, stream>>>(Wk, Wkh, Wkl, DM * DM / 4);
    split_f32<<<(DM * DM / 4 + 255) / 256, 256, 0, stream>>>(Wv, Wvh, Wvl, DM * DM / 4);
    split_f32<<<(DM * DM / 4 + 255) / 256, 256, 0, stream>>>(Wo, Woh, Wol, DM * DM / 4);

    dim3 ggrid(DM / 128, MTOT / 128);   // (8, 64)
    gemm_split<1><<<ggrid, 256, 0, stream>>>(Xh, Xl, Wqh, Wql, bq, nullptr, qh, ql);
    gemm_split<1><<<ggrid, 256, 0, stream>>>(Xh, Xl, Wkh, Wkl, bk, nullptr, kh, kl);
    gemm_split<2><<<ggrid, 256, 0, stream>>>(Xh, Xl, Wvh, Wvl, bv, nullptr, vh, vl);

    flash_mfma4<<<dim3(SEQ / 128, 4 * NH), 256, 0, stream>>>(qh, ql, kh, kl, vh, vl, am, Xh, Xl);

    gemm_split<0><<<ggrid, 256, 0, stream>>>(Xh, Xl, Woh, Wol, bo, out, nullptr, nullptr);
}